// Round 3
// baseline (238.505 us; speedup 1.0000x reference)
//
#include <hip/hip_runtime.h>
#include <hip/hip_bf16.h>
#include <stdint.h>

#define C_DIM 256
#define N_DIM 4096
#define B_DIM 4

typedef __attribute__((ext_vector_type(8))) short s16x8;   // 8 bf16
typedef __attribute__((ext_vector_type(4))) short s16x4;   // 4 bf16
typedef __attribute__((ext_vector_type(4))) float f32x4;
typedef __attribute__((ext_vector_type(16))) float f32x16;

static __device__ __forceinline__ short f2bs(float f) {
    __bf16 h = (__bf16)f;                 // RNE f32->bf16
    return __builtin_bit_cast(short, h);
}

// ---------------------------------------------------------------------------
// Kernel 0: transpose+convert x,y -> xT,yT [B][N][C] bf16; convert weights.
// ---------------------------------------------------------------------------
__global__ __launch_bounds__(256)
void prep_kernel(const float* __restrict__ x, const float* __restrict__ y,
                 const float* __restrict__ wq, const float* __restrict__ wk,
                 const float* __restrict__ wv,
                 short* __restrict__ xT, short* __restrict__ yT,
                 short* __restrict__ wb)
{
    int bid = blockIdx.x;
    int t = threadIdx.x;
    if (bid < 2048) {
        const float* src = (bid < 1024) ? x : y;
        short* dst = (bid < 1024) ? xT : yT;
        int id = bid & 1023;
        int ct = id & 3;            // 4 c-tiles of 64
        int nt = (id >> 2) & 63;    // 64 n-tiles of 64
        int b  = id >> 8;           // 4 batches
        int n0 = nt * 64, c0 = ct * 64;
        __shared__ short T[64][66]; // odd dword stride -> conflict-free
        int l = t & 63;
        int wv_ = t >> 6;
        #pragma unroll
        for (int p = 0; p < 16; ++p) {
            int c = wv_ + p * 4;
            float v = src[((size_t)(b * C_DIM + c0 + c)) * N_DIM + n0 + l];
            T[l][c] = f2bs(v);
        }
        __syncthreads();
        #pragma unroll
        for (int p = 0; p < 16; ++p) {
            int n = wv_ + p * 4;
            dst[((size_t)(b * N_DIM + n0 + n)) * C_DIM + c0 + l] = T[n][l];
        }
    } else {
        // weights: 96 blocks x 2048 elems
        int id = bid - 2048;
        const float* w = (id < 32) ? wq : (id < 64) ? wk : wv;
        short* dst = wb + (size_t)(id / 32) * (C_DIM * C_DIM);
        int off = (id & 31) * 2048 + t * 8;
        f32x4 a  = *(const f32x4*)(w + off);
        f32x4 b4 = *(const f32x4*)(w + off + 4);
        s16x8 r;
        r[0]=f2bs(a[0]);  r[1]=f2bs(a[1]);  r[2]=f2bs(a[2]);  r[3]=f2bs(a[3]);
        r[4]=f2bs(b4[0]); r[5]=f2bs(b4[1]); r[6]=f2bs(b4[2]); r[7]=f2bs(b4[3]);
        *(s16x8*)(dst + off) = r;
    }
}

// ---------------------------------------------------------------------------
// Kernel 1: projections. Qb,Kb = [B][N][256]; Vb = [B][256][N].
// Q is pre-scaled by log2(e) so attention softmax can use exp2 directly.
// ---------------------------------------------------------------------------
__global__ __launch_bounds__(256)
void proj_kernel(const short* __restrict__ xT, const short* __restrict__ yT,
                 const short* __restrict__ wb,
                 short* __restrict__ Qb, short* __restrict__ Kb,
                 short* __restrict__ Vb)
{
    int bid = blockIdx.x;              // 3072 = 12 * 64 * 4
    int ot = bid & 3;
    int nt = (bid >> 2) & 63;
    int bp = bid >> 8;                 // 0..11 = b*3 + p
    int b = bp / 3, p = bp % 3;
    int n0 = nt * 64, o0 = ot * 64;
    const short* src = (p == 0) ? xT : yT;
    const short* w = wb + (size_t)p * C_DIM * C_DIM;

    __shared__ __align__(16) short Xs[64][264];

    int t = threadIdx.x;
    const short* srcb = src + (size_t)(b * N_DIM + n0) * C_DIM;
    #pragma unroll
    for (int pas = 0; pas < 8; ++pas) {
        int slot = pas * 256 + t;
        int row = slot >> 5, ck = slot & 31;
        *(s16x8*)&Xs[row][ck * 8] = *(const s16x8*)&srcb[(size_t)row * C_DIM + ck * 8];
    }
    __syncthreads();

    int lane = t & 63;
    int wid = t >> 6;
    int m = lane & 15, q = lane >> 4;
    f32x4 acc[4] = {};

    if (p < 2) {
        #pragma unroll
        for (int kk = 0; kk < 8; ++kk) {
            s16x8 af = *(const s16x8*)&Xs[wid * 16 + m][kk * 32 + q * 8];
            #pragma unroll
            for (int ob = 0; ob < 4; ++ob) {
                s16x8 bf = *(const s16x8*)&w[(size_t)(o0 + ob * 16 + m) * C_DIM + kk * 32 + q * 8];
                acc[ob] = __builtin_amdgcn_mfma_f32_16x16x32_bf16(af, bf, acc[ob], 0, 0, 0);
            }
        }
        float sc = (p == 0) ? 1.4426950408889634f : 1.0f;  // log2(e) for Q
        short* dst = ((p == 0) ? Qb : Kb) + (size_t)b * N_DIM * C_DIM;
        #pragma unroll
        for (int ob = 0; ob < 4; ++ob)
            #pragma unroll
            for (int r = 0; r < 4; ++r) {
                int n = n0 + wid * 16 + q * 4 + r;
                int o = o0 + ob * 16 + m;
                dst[(size_t)n * C_DIM + o] = f2bs(acc[ob][r] * sc);
            }
    } else {
        #pragma unroll
        for (int kk = 0; kk < 8; ++kk) {
            s16x8 af = *(const s16x8*)&w[(size_t)(o0 + wid * 16 + m) * C_DIM + kk * 32 + q * 8];
            #pragma unroll
            for (int nb = 0; nb < 4; ++nb) {
                s16x8 bf = *(const s16x8*)&Xs[nb * 16 + m][kk * 32 + q * 8];
                acc[nb] = __builtin_amdgcn_mfma_f32_16x16x32_bf16(af, bf, acc[nb], 0, 0, 0);
            }
        }
        short* dst = Vb + (size_t)b * C_DIM * N_DIM;
        #pragma unroll
        for (int nb = 0; nb < 4; ++nb)
            #pragma unroll
            for (int r = 0; r < 4; ++r) {
                int o = o0 + wid * 16 + q * 4 + r;
                int n = n0 + nb * 16 + m;
                dst[(size_t)o * N_DIM + n] = f2bs(acc[nb][r]);
            }
    }
}

// ---------------------------------------------------------------------------
// Kernel 2: flash attention + epilogue. Producer-consumer skewed pipeline.
//
// KVBLK=64, 64 q-rows/block, 8 waves:
//   Waves 0-3 "QK" (jb = w&1, qh = w>>1): S^T[32k][32q] = mfma(A=K rows,
//     B=Q regs); 2 independent 8-chains; in-lane max + xor32 -> mpart.
//     Phase B: softmax (exp2, Q pre-scaled log2e), P+spart+alpha write.
//   Waves 4-7 "PV" (cbase = (w-4)*64): O^T[64c][64q] over tile jt-1 =
//     mfma(A=V rows, B=P); 4 independent 4-chains. Phase A: rescale by
//     alpha(jt-1), PV MFMAs, issue next K/V global loads. Phase B: LDS
//     stage-writes.
// PV runs ONE TILE BEHIND QK: in phase A, QK-MFMA || PV-MFMA || prefetch;
// in phase B, softmax-VALU || stage-writes. Each SIMD carries 1 QK + 1 PV
// wave. All LDS buffers single-buffered (skew + 2 barriers/tile separate
// every write from its readers).
// ---------------------------------------------------------------------------
__global__ __launch_bounds__(512, 2)
void attn_kernel(const short* __restrict__ Qb, const short* __restrict__ Kb,
                 const short* __restrict__ Vb, const float* __restrict__ x,
                 const float* __restrict__ gamma, float* __restrict__ out)
{
    int bid0 = blockIdx.x;
    int bid = (bid0 & 7) * 32 + (bid0 >> 3);   // XCD swizzle: 32 same-batch blocks/XCD
    int b = bid >> 6, it = bid & 63;
    int i0 = it * 64;

    int t = threadIdx.x;
    int w = t >> 6;
    int lane = t & 63;
    int il = lane & 31;
    int hi = lane >> 5;

    bool isQK = (w < 4);
    int jb = w & 1;              // QK: key 32-block within tile
    int qh = w >> 1;             // QK: query half
    int cbase = (w - 4) * 64;    // PV: channel strip base

    __shared__ __align__(16) short Ks[64][264];    // 33.8 KB
    __shared__ __align__(16) short Vs[256][72];    // 36.9 KB
    __shared__ __align__(16) short Ps[64][72];     //  9.2 KB
    __shared__ float mpart[2][64];
    __shared__ float spart[2][64];
    __shared__ float alphas[64];

    const short* Qp = Qb + (size_t)b * N_DIM * C_DIM;
    const short* Kp = Kb + (size_t)b * N_DIM * C_DIM;
    const short* Vp = Vb + (size_t)b * C_DIM * N_DIM;

    // Q fragments (QK waves): B[k=c][col=q], lane holds q = qh*32+il
    s16x8 qf[16];
    if (isQK) {
        const short* qrow = Qp + (size_t)(i0 + qh * 32 + il) * C_DIM + hi * 8;
        #pragma unroll
        for (int kk = 0; kk < 16; ++kk)
            qf[kk] = *(const s16x8*)&qrow[kk * 16];
    }

    // prologue: all 8 waves stage K tile 0 (64 rows x 256 c)
    {
        int row4 = t >> 5, g4 = t & 31;
        #pragma unroll
        for (int p = 0; p < 4; ++p) {
            s16x8 v = *(const s16x8*)&Kp[(size_t)(p * 16 + row4) * C_DIM + g4 * 8];
            *(s16x8*)&Ks[p * 16 + row4][g4 * 8] = v;
        }
    }
    __syncthreads();

    // PV state
    f32x16 acc00 = {}, acc01 = {}, acc10 = {}, acc11 = {};  // [cb][qh]
    float srA = 0.f, srB = 0.f;
    s16x8 kreg[8], vreg[8];
    int u = t & 255;              // PV staging thread id
    int krow = u >> 5, kg = u & 31;   // K: rows p*8+krow, granule kg
    int vrow = u >> 3, vg = u & 7;    // V: rows p*32+vrow, granule vg

    // QK state
    float mrun = -3e38f;
    f32x16 sv;

    for (int jt = 0; jt < 64; ++jt) {
        // ---- Phase A: QK(jt) MFMA || PV(jt-1) MFMA || prefetch issue ------
        if (isQK) {
            f32x16 sv0 = {}, sv1 = {};
            __builtin_amdgcn_s_setprio(1);
            #pragma unroll
            for (int kk = 0; kk < 8; ++kk) {
                s16x8 a0 = *(const s16x8*)&Ks[jb * 32 + il][kk * 16 + hi * 8];
                sv0 = __builtin_amdgcn_mfma_f32_32x32x16_bf16(a0, qf[kk], sv0, 0, 0, 0);
                s16x8 a1 = *(const s16x8*)&Ks[jb * 32 + il][(kk + 8) * 16 + hi * 8];
                sv1 = __builtin_amdgcn_mfma_f32_32x32x16_bf16(a1, qf[kk + 8], sv1, 0, 0, 0);
            }
            __builtin_amdgcn_s_setprio(0);
            #pragma unroll
            for (int r = 0; r < 16; ++r) sv[r] = sv0[r] + sv1[r];
            float tmax = sv[0];
            #pragma unroll
            for (int r = 1; r < 16; ++r) tmax = fmaxf(tmax, sv[r]);
            tmax = fmaxf(tmax, __shfl_xor(tmax, 32, 64));
            if (hi == 0) mpart[jb][qh * 32 + il] = tmax;
        } else {
            // issue next-tile global loads first (fire early)
            if (jt < 63) {
                const short* kgp = Kp + (size_t)(jt + 1) * 64 * C_DIM;
                #pragma unroll
                for (int p = 0; p < 8; ++p)
                    kreg[p] = *(const s16x8*)&kgp[(size_t)(p * 8 + krow) * C_DIM + kg * 8];
            }
            {
                const short* vgp = Vp + (size_t)jt * 64;
                #pragma unroll
                for (int p = 0; p < 8; ++p)
                    vreg[p] = *(const s16x8*)&vgp[(size_t)(p * 32 + vrow) * N_DIM + vg * 8];
            }
            if (jt > 0) {
                float aA = alphas[il], aB = alphas[32 + il];
                if (__any(aA != 1.f)) {
                    #pragma unroll
                    for (int r = 0; r < 16; ++r) { acc00[r] *= aA; acc10[r] *= aA; }
                }
                if (__any(aB != 1.f)) {
                    #pragma unroll
                    for (int r = 0; r < 16; ++r) { acc01[r] *= aB; acc11[r] *= aB; }
                }
                srA = srA * aA + spart[0][il] + spart[1][il];
                srB = srB * aB + spart[0][32 + il] + spart[1][32 + il];
                __builtin_amdgcn_s_setprio(1);
                #pragma unroll
                for (int ks = 0; ks < 4; ++ks) {
                    s16x8 b0 = *(const s16x8*)&Ps[il][ks * 16 + hi * 8];
                    s16x8 b1 = *(const s16x8*)&Ps[32 + il][ks * 16 + hi * 8];
                    s16x8 a0 = *(const s16x8*)&Vs[cbase + il][ks * 16 + hi * 8];
                    s16x8 a1 = *(const s16x8*)&Vs[cbase + 32 + il][ks * 16 + hi * 8];
                    acc00 = __builtin_amdgcn_mfma_f32_32x32x16_bf16(a0, b0, acc00, 0, 0, 0);
                    acc01 = __builtin_amdgcn_mfma_f32_32x32x16_bf16(a0, b1, acc01, 0, 0, 0);
                    acc10 = __builtin_amdgcn_mfma_f32_32x32x16_bf16(a1, b0, acc10, 0, 0, 0);
                    acc11 = __builtin_amdgcn_mfma_f32_32x32x16_bf16(a1, b1, acc11, 0, 0, 0);
                }
                __builtin_amdgcn_s_setprio(0);
            }
        }
        __syncthreads();   // bar1: mpart ready; Ks/Vs/Ps reads done

        // ---- Phase B: softmax + P write (QK) || stage-writes (PV) ---------
        if (isQK) {
            float m0 = mpart[0][qh * 32 + il], m1 = mpart[1][qh * 32 + il];
            float mnew = fmaxf(mrun, fmaxf(m0, m1));
            float alpha = exp2f(mrun - mnew);
            mrun = mnew;
            if (jb == 0 && hi == 0) alphas[qh * 32 + il] = alpha;
            float ts = 0.f;
            #pragma unroll
            for (int r = 0; r < 16; ++r) {
                float pe = exp2f(sv[r] - mnew);   // Q pre-scaled by log2(e)
                sv[r] = pe;
                ts += pe;
            }
            ts += __shfl_xor(ts, 32, 64);
            if (hi == 0) spart[jb][qh * 32 + il] = ts;
            // P rows j = jb*32 + 8g + 4hi + (0..3), col q = qh*32+il
            #pragma unroll
            for (int g = 0; g < 4; ++g) {
                s16x4 pv;
                pv[0] = f2bs(sv[4 * g + 0]); pv[1] = f2bs(sv[4 * g + 1]);
                pv[2] = f2bs(sv[4 * g + 2]); pv[3] = f2bs(sv[4 * g + 3]);
                *(s16x4*)&Ps[qh * 32 + il][jb * 32 + g * 8 + hi * 4] = pv;
            }
        } else {
            if (jt < 63) {
                #pragma unroll
                for (int p = 0; p < 8; ++p)
                    *(s16x8*)&Ks[p * 8 + krow][kg * 8] = kreg[p];
            }
            #pragma unroll
            for (int p = 0; p < 8; ++p)
                *(s16x8*)&Vs[p * 32 + vrow][vg * 8] = vreg[p];
        }
        __syncthreads();   // bar2: P/spart/alpha + next K + cur V staged
    }

    // ---- tail: PV for tile 63, then epilogue (PV waves only) --------------
    if (!isQK) {
        float aA = alphas[il], aB = alphas[32 + il];
        if (__any(aA != 1.f)) {
            #pragma unroll
            for (int r = 0; r < 16; ++r) { acc00[r] *= aA; acc10[r] *= aA; }
        }
        if (__any(aB != 1.f)) {
            #pragma unroll
            for (int r = 0; r < 16; ++r) { acc01[r] *= aB; acc11[r] *= aB; }
        }
        srA = srA * aA + spart[0][il] + spart[1][il];
        srB = srB * aB + spart[0][32 + il] + spart[1][32 + il];
        #pragma unroll
        for (int ks = 0; ks < 4; ++ks) {
            s16x8 b0 = *(const s16x8*)&Ps[il][ks * 16 + hi * 8];
            s16x8 b1 = *(const s16x8*)&Ps[32 + il][ks * 16 + hi * 8];
            s16x8 a0 = *(const s16x8*)&Vs[cbase + il][ks * 16 + hi * 8];
            s16x8 a1 = *(const s16x8*)&Vs[cbase + 32 + il][ks * 16 + hi * 8];
            acc00 = __builtin_amdgcn_mfma_f32_32x32x16_bf16(a0, b0, acc00, 0, 0, 0);
            acc01 = __builtin_amdgcn_mfma_f32_32x32x16_bf16(a0, b1, acc01, 0, 0, 0);
            acc10 = __builtin_amdgcn_mfma_f32_32x32x16_bf16(a1, b0, acc10, 0, 0, 0);
            acc11 = __builtin_amdgcn_mfma_f32_32x32x16_bf16(a1, b1, acc11, 0, 0, 0);
        }

        float g = gamma[0];
        float invA = 1.f / srA;
        float invB = 1.f / srB;
        #pragma unroll
        for (int r = 0; r < 16; ++r) {
            int cofs = (r & 3) + 8 * (r >> 2) + 4 * hi;
            {
                int c = cbase + cofs;
                size_t idxA = ((size_t)(b * C_DIM + c)) * N_DIM + i0 + il;
                out[idxA] = g * acc00[r] * invA + x[idxA];
                size_t idxB = idxA + 32;
                out[idxB] = g * acc01[r] * invB + x[idxB];
            }
            {
                int c = cbase + 32 + cofs;
                size_t idxA = ((size_t)(b * C_DIM + c)) * N_DIM + i0 + il;
                out[idxA] = g * acc10[r] * invA + x[idxA];
                size_t idxB = idxA + 32;
                out[idxB] = g * acc11[r] * invB + x[idxB];
            }
        }
    }
}

// ---------------------------------------------------------------------------
extern "C" void kernel_launch(void* const* d_in, const int* in_sizes, int n_in,
                              void* d_out, int out_size, void* d_ws, size_t ws_size,
                              hipStream_t stream) {
    const float* x  = (const float*)d_in[0];
    const float* y  = (const float*)d_in[1];
    const float* wq = (const float*)d_in[2];
    const float* wk = (const float*)d_in[3];
    const float* wv = (const float*)d_in[4];
    const float* gm = (const float*)d_in[5];
    float* out = (float*)d_out;

    char* ws = (char*)d_ws;
    const size_t SZ = (size_t)B_DIM * N_DIM * C_DIM * sizeof(short); // 8 MB
    short* xT = (short*)(ws);
    short* yT = (short*)(ws + SZ);
    short* Qb = (short*)(ws + 2 * SZ);
    short* Kb = (short*)(ws + 3 * SZ);
    short* Vb = (short*)(ws + 4 * SZ);
    short* wb = (short*)(ws + 5 * SZ); // 384 KB

    prep_kernel<<<dim3(2048 + 96), dim3(256), 0, stream>>>(x, y, wq, wk, wv, xT, yT, wb);
    proj_kernel<<<dim3(3072), dim3(256), 0, stream>>>(xT, yT, wb, Qb, Kb, Vb);
    attn_kernel<<<dim3(256), dim3(512), 0, stream>>>(Qb, Kb, Vb, x, gm, out);
}